// Round 11
// baseline (750.696 us; speedup 1.0000x reference)
//
#include <hip/hip_runtime.h>
#include <hip/hip_cooperative_groups.h>
#include <hip/hip_bf16.h>
#include <float.h>
#include <math.h>

namespace cg = cooperative_groups;

#define N_NODES 1024
#define N_EDGES 524288
#define IN_C    64
#define HID_C   128
#define OUT_C   512
#define MLP_H   64
#define ADJ_WORDS 32   // 1024 bits per dst row
#define NCOPY   8      // privatized adjacency copies
#define ADJ_CSZ (N_NODES * ADJ_WORDS)  // words per copy (32768)
#define KSPLIT_M 16    // mega-kernel readout split (R6's proven numeric path)
#define KSPLIT_F 8     // fallback readout split (R10 path)

typedef __attribute__((ext_vector_type(8))) short short8;
typedef __attribute__((ext_vector_type(4))) float f32x4;

static __device__ __forceinline__ unsigned short f2bf(float f) {
    __hip_bfloat16 h = __float2bfloat16(f);
    return __builtin_bit_cast(unsigned short, h);
}

// pack fp32 W[64][C] into bf16 MFMA B-fragments: Wpk[nt][kf][lane][8]
static __device__ __forceinline__ void pack_w_one(
        const float* __restrict__ W, unsigned short* __restrict__ Wpk, int C, int idx) {
    int lane = idx & 63;
    int kf = (idx >> 6) & 1;
    int nt = idx >> 7;
    int kbase = kf * 32 + (lane >> 4) * 8;
    int c = nt * 16 + (lane & 15);
#pragma unroll
    for (int e = 0; e < 8; ++e)
        Wpk[idx * 8 + e] = f2bf(W[(kbase + e) * C + c]);
}

struct MegaParams {
    const float* x; const int* ei;
    const float* W1; const float* b1;
    const float* W2; const float* b2;
    const float* W3; const float* b3;
    const float* W4; const float* b4;
    const float* Wr; const float* br;
    unsigned int* adj;
    float* A1; float* B1; float* A2; float* B2; float* h2;
    unsigned short* Wpk1; unsigned short* Wpk2;
    float* partial;
    float* out;
};

// ---------------------------------------------------------------------------
// conv phase (shared by mega + fallback via template over LDS access):
// fused edge-MLP second layer + segment-max via MFMA bf16, cooperative build,
// double-buffered LDS z-tiles, register W-fragments, setprio on MFMA cluster.
// ---------------------------------------------------------------------------
template <int NTILES, int C_TOTAL, bool FUSEX>
static __device__ void conv_phase(
        char* smraw,
        const unsigned int* __restrict__ adj,
        const float* __restrict__ Anode, const float* __restrict__ Bnode,
        const unsigned short* __restrict__ Wpk, const float* __restrict__ bias_g,
        float* __restrict__ outv,
        const float* __restrict__ W3, const float* __restrict__ b3,
        float* __restrict__ A2out, float* __restrict__ B2out) {
    constexpr int BATCH = 8;
    unsigned short* list = (unsigned short*)smraw;                       // 2080 B
    auto zbuf = (short8 (*)[BATCH][2][64])(smraw + 2080);                // 32768 B
    float* hrow = (float*)(smraw + 2080 + 32768);                        // 512 B
    float* xsum = hrow + HID_C;                                          // 512 B
    int* cntp = (int*)(xsum + HID_C);

    const int i = blockIdx.x;
    const int tid = threadIdx.x;
    const int lane = tid & 63;
    const int wave = tid >> 6;
    const int g = lane >> 4;
    const int r = lane & 15;

    // W fragments + A[dst] hoisted: latency hides under wave-0 scan
    short8 wfr[NTILES][2];
#pragma unroll
    for (int n = 0; n < NTILES; ++n) {
        int nt = wave * NTILES + n;
#pragma unroll
        for (int kf = 0; kf < 2; ++kf)
            wfr[n][kf] = ((const short8*)Wpk)[(nt * 2 + kf) * 64 + lane];
    }
    const f32x4* Ap = (const f32x4*)(Anode + i * MLP_H);
    f32x4 a0 = Ap[g * 2], a1 = Ap[g * 2 + 1], a2 = Ap[8 + g * 2], a3 = Ap[9 + g * 2];

    // wave 0: merge 8 privatized copies + popcount prefix-scan compaction
    if (wave == 0) {
        unsigned int bits = 0u;
        if (lane < ADJ_WORDS) {
            const unsigned int* ap = adj + i * ADJ_WORDS + lane;
#pragma unroll
            for (int c = 0; c < NCOPY; ++c) bits |= ap[c * ADJ_CSZ];
        }
        int c = __popc(bits);
        int pre = c;
#pragma unroll
        for (int d = 1; d < 64; d <<= 1) {
            int t = __shfl_up(pre, d);
            if (lane >= d) pre += t;
        }
        int total = __shfl(pre, 63);
        int pos = pre - c;
        while (bits) {
            int b = __ffs(bits) - 1;
            bits &= bits - 1;
            list[pos++] = (unsigned short)(lane * 32 + b);
        }
        if (lane == 0) *cntp = total;
    }
    __syncthreads();
    const int deg = *cntp;
    const int padded = (deg + 15) & ~15;
    for (int p = deg + tid; p < padded; p += 256) list[p] = list[0];

    float mx[NTILES];
#pragma unroll
    for (int n = 0; n < NTILES; ++n) mx[n] = -INFINITY;

    auto build = [&](int buf, int base_tile, int ntl) {
#pragma unroll
        for (int u = 0; u < BATCH / 4; ++u) {
            int tt = u * 4 + wave;
            if (tt < ntl) {
                int j = list[(base_tile + tt) * 16 + r];
                const f32x4* Bp = (const f32x4*)(Bnode + (size_t)j * MLP_H);
                f32x4 b0 = Bp[g * 2], b1 = Bp[g * 2 + 1], b2 = Bp[8 + g * 2], b3v = Bp[9 + g * 2];
                f32x4 s0 = a0 + b0, s1 = a1 + b1, s2 = a2 + b2, s3 = a3 + b3v;
                short8 z0, z1;
#pragma unroll
                for (int e = 0; e < 4; ++e) {
                    z0[e]     = (short)f2bf(fmaxf(s0[e], 0.f));
                    z0[e + 4] = (short)f2bf(fmaxf(s1[e], 0.f));
                    z1[e]     = (short)f2bf(fmaxf(s2[e], 0.f));
                    z1[e + 4] = (short)f2bf(fmaxf(s3[e], 0.f));
                }
                zbuf[buf][tt][0][lane] = z0;
                zbuf[buf][tt][1][lane] = z1;
            }
        }
    };

    const int ntiles_e = padded >> 4;
    const f32x4 zero = {0.f, 0.f, 0.f, 0.f};

    __syncthreads();
    build(0, 0, min(BATCH, ntiles_e));
    __syncthreads();

    int cur = 0;
    for (int b0 = 0; b0 < ntiles_e; b0 += BATCH) {
        int nb = min(BATCH, ntiles_e - b0);
        int nxt = b0 + BATCH;
        if (nxt < ntiles_e) build(cur ^ 1, nxt, min(BATCH, ntiles_e - nxt));
        __builtin_amdgcn_s_setprio(1);
        for (int tt = 0; tt < nb; ++tt) {
            short8 z0 = zbuf[cur][tt][0][lane];
            short8 z1 = zbuf[cur][tt][1][lane];
#pragma unroll
            for (int n = 0; n < NTILES; ++n) {
                f32x4 acc = __builtin_amdgcn_mfma_f32_16x16x32_bf16(z0, wfr[n][0], zero, 0, 0, 0);
                acc = __builtin_amdgcn_mfma_f32_16x16x32_bf16(z1, wfr[n][1], acc, 0, 0, 0);
                mx[n] = fmaxf(mx[n], fmaxf(fmaxf(acc[0], acc[1]), fmaxf(acc[2], acc[3])));
            }
        }
        __builtin_amdgcn_s_setprio(0);
        __syncthreads();
        cur ^= 1;
    }

#pragma unroll
    for (int n = 0; n < NTILES; ++n) {
        mx[n] = fmaxf(mx[n], __shfl_xor(mx[n], 16));
        mx[n] = fmaxf(mx[n], __shfl_xor(mx[n], 32));
    }
    if (lane < 16) {
#pragma unroll
        for (int n = 0; n < NTILES; ++n) {
            int c = (wave * NTILES + n) * 16 + lane;
            float hv = (deg == 0) ? 0.f : mx[n] + bias_g[c];
            if constexpr (FUSEX) hrow[c] = hv;
            else                 outv[i * C_TOTAL + c] = hv;
        }
    }

    if constexpr (FUSEX) {
        __syncthreads();
        const int c = tid & 63;
        const int half = (tid >> 6) & 1;
        const int ksel = tid >> 7;
        const float* wp = W3 + (half * 128 + ksel * 64) * MLP_H + c;
        float s = 0.f;
#pragma unroll
        for (int k = 0; k < 64; ++k)
            s = fmaf(hrow[ksel * 64 + k], wp[k * MLP_H], s);
        if (ksel) xsum[half * 64 + c] = s;
        __syncthreads();
        if (!ksel) {
            s += xsum[half * 64 + c];
            if (half == 0) A2out[i * MLP_H + c] = s + b3[c];
            else           B2out[i * MLP_H + c] = s;
        }
    }
}

// ---------------------------------------------------------------------------
// Mega cooperative kernel: all 6 phases, 5 grid.sync()s, zero launch gaps.
// 1024 blocks x 256 thr = exactly 4 blocks/CU (LDS 35.9KB, VGPR<=128).
// ---------------------------------------------------------------------------
__global__ __launch_bounds__(256, 4) void k_mega(MegaParams p) {
    cg::grid_group grid = cg::this_grid();
    __shared__ __align__(16) char smraw[35904];
    const int bid = blockIdx.x, tid = threadIdx.x;
    const int gid = bid * 256 + tid;

    // ---- P0: zero adj copies + pack W + xform1 ----
    p.adj[gid] = 0u;  // 262144 words == grid size
    if (bid >= 256 && bid < 260) {
        pack_w_one(p.W2, p.Wpk1, HID_C, (bid - 256) * 256 + tid);
    } else if (bid >= 260 && bid < 276) {
        pack_w_one(p.W4, p.Wpk2, OUT_C, (bid - 260) * 256 + tid);
    } else if (bid < 256) {
        float (*xs)[IN_C] = (float (*)[IN_C])smraw;
        const int sub = tid >> 6, t = tid & 63;
        const int n = bid * 4 + sub;
        xs[sub][t] = p.x[n * IN_C + t];
        __syncthreads();
        float a = p.b1[t], bb = 0.f;
#pragma unroll
        for (int k = 0; k < IN_C; ++k) {
            float xv = xs[sub][k];
            a = fmaf(xv, p.W1[k * MLP_H + t], a);
            bb = fmaf(xv, p.W1[(IN_C + k) * MLP_H + t], bb);
        }
        p.A1[n * MLP_H + t] = a;
        p.B1[n * MLP_H + t] = bb;
    }
    grid.sync();

    // ---- P1: build adjacency bitmap (privatized, grid-stride) ----
    {
        unsigned int* base = p.adj + (bid & (NCOPY - 1)) * ADJ_CSZ;
        for (int e = gid; e < N_EDGES; e += 1024 * 256) {
            int src = p.ei[e];
            int dst = p.ei[N_EDGES + e];
            atomicOr(&base[dst * ADJ_WORDS + (src >> 5)], 1u << (src & 31));
        }
    }
    grid.sync();

    // ---- P2: conv1 + fused xform2 ----
    conv_phase<2, HID_C, true>(smraw, p.adj, p.A1, p.B1, p.Wpk1, p.b2,
                               nullptr, p.W3, p.b3, p.A2, p.B2);
    grid.sync();

    // ---- P3: conv2 ----
    conv_phase<8, OUT_C, false>(smraw, p.adj, p.A2, p.B2, p.Wpk2, p.b4,
                                p.h2, nullptr, nullptr, nullptr, nullptr);
    grid.sync();

    // ---- P4: readout partials (KSPLIT=16, single 64-deep stage/block) ----
    {
        float (*As)[64] = (float (*)[64])smraw;
        float (*Bs)[64] = (float (*)[64])(smraw + 16384);
        const int kc = bid >> 6;
        const int tile = bid & 63;
        const int c0 = (tile >> 3) * 64;
        const int o0 = (tile & 7) * 64;
        const int k0 = kc * (N_NODES / KSPLIT_M);
        const int tx = tid & 15, ty = tid >> 4;
        for (int s = tid; s < 1024; s += 256) {
            int rr = s >> 4;
            int cq = (s & 15) * 4;
            *(float4*)&As[rr][cq] = *(const float4*)&p.h2[(k0 + rr) * OUT_C + c0 + cq];
            *(float4*)&Bs[rr][cq] = *(const float4*)&p.Wr[(k0 + rr) * OUT_C + o0 + cq];
        }
        __syncthreads();
        float acc[4][4] = {};
#pragma unroll 16
        for (int kk = 0; kk < 64; ++kk) {
            float4 a = *(float4*)&As[kk][ty * 4];
            float4 b = *(float4*)&Bs[kk][tx * 4];
            acc[0][0] = fmaf(a.x, b.x, acc[0][0]); acc[0][1] = fmaf(a.x, b.y, acc[0][1]);
            acc[0][2] = fmaf(a.x, b.z, acc[0][2]); acc[0][3] = fmaf(a.x, b.w, acc[0][3]);
            acc[1][0] = fmaf(a.y, b.x, acc[1][0]); acc[1][1] = fmaf(a.y, b.y, acc[1][1]);
            acc[1][2] = fmaf(a.y, b.z, acc[1][2]); acc[1][3] = fmaf(a.y, b.w, acc[1][3]);
            acc[2][0] = fmaf(a.z, b.x, acc[2][0]); acc[2][1] = fmaf(a.z, b.y, acc[2][1]);
            acc[2][2] = fmaf(a.z, b.z, acc[2][2]); acc[2][3] = fmaf(a.z, b.w, acc[2][3]);
            acc[3][0] = fmaf(a.w, b.x, acc[3][0]); acc[3][1] = fmaf(a.w, b.y, acc[3][1]);
            acc[3][2] = fmaf(a.w, b.z, acc[3][2]); acc[3][3] = fmaf(a.w, b.w, acc[3][3]);
        }
        float* pb = p.partial + (size_t)kc * (OUT_C * OUT_C);
#pragma unroll
        for (int u = 0; u < 4; ++u) {
            float4 v = {acc[u][0], acc[u][1], acc[u][2], acc[u][3]};
            *(float4*)&pb[(c0 + ty * 4 + u) * OUT_C + o0 + tx * 4] = v;
        }
    }
    grid.sync();

    // ---- P5: reduce 16 partials + bias -> out ----
    if (gid < 65536) {
        const float4* p4 = (const float4*)p.partial;
        float4 s = p4[gid];
#pragma unroll
        for (int k = 1; k < KSPLIT_M; ++k) {
            float4 t = p4[gid + k * 65536];
            s.x += t.x; s.y += t.y; s.z += t.z; s.w += t.w;
        }
        float4 b = ((const float4*)p.br)[gid & 127];
        s.x += b.x; s.y += b.y; s.z += b.z; s.w += b.w;
        ((float4*)p.out)[gid] = s;
    }
}

// ===========================================================================
// Fallback path (R10 kernels) if cooperative launch is rejected.
// ===========================================================================
__global__ __launch_bounds__(256) void k_init(
        unsigned int* __restrict__ adj,
        const float* __restrict__ W2, unsigned short* __restrict__ Wpk1,
        const float* __restrict__ W4, unsigned short* __restrict__ Wpk2,
        const float* __restrict__ x, const float* __restrict__ W1,
        const float* __restrict__ b1,
        float* __restrict__ A1, float* __restrict__ B1) {
    __shared__ float xs[4][IN_C];
    const int b = blockIdx.x, tid = threadIdx.x;
    if (b < 1024) { adj[b * 256 + tid] = 0u; return; }
    if (b < 1028) { pack_w_one(W2, Wpk1, HID_C, (b - 1024) * 256 + tid); return; }
    if (b < 1044) { pack_w_one(W4, Wpk2, OUT_C, (b - 1028) * 256 + tid); return; }
    const int sub = tid >> 6, t = tid & 63;
    const int n = (b - 1044) * 4 + sub;
    xs[sub][t] = x[n * IN_C + t];
    __syncthreads();
    float a = b1[t], bb = 0.f;
#pragma unroll
    for (int k = 0; k < IN_C; ++k) {
        float xv = xs[sub][k];
        a = fmaf(xv, W1[k * MLP_H + t], a);
        bb = fmaf(xv, W1[(IN_C + k) * MLP_H + t], bb);
    }
    A1[n * MLP_H + t] = a;
    B1[n * MLP_H + t] = bb;
}

__global__ void k_build_adj(const int* __restrict__ ei, unsigned int* __restrict__ adj) {
    int e = blockIdx.x * blockDim.x + threadIdx.x;
    if (e >= N_EDGES) return;
    int src = ei[e];
    int dst = ei[N_EDGES + e];
    unsigned int* base = adj + (blockIdx.x & (NCOPY - 1)) * ADJ_CSZ;
    atomicOr(&base[dst * ADJ_WORDS + (src >> 5)], 1u << (src & 31));
}

template <int NTILES, int C_TOTAL, bool FUSEX>
__global__ __launch_bounds__(256, 4) void k_conv_mfma(
        const unsigned int* __restrict__ adj,
        const float* __restrict__ Anode, const float* __restrict__ Bnode,
        const unsigned short* __restrict__ Wpk, const float* __restrict__ bias_g,
        float* __restrict__ outv,
        const float* __restrict__ W3, const float* __restrict__ b3,
        float* __restrict__ A2out, float* __restrict__ B2out) {
    __shared__ __align__(16) char smraw[35904];
    conv_phase<NTILES, C_TOTAL, FUSEX>(smraw, adj, Anode, Bnode, Wpk, bias_g,
                                       outv, W3, b3, A2out, B2out);
}

__global__ __launch_bounds__(256) void k_readout_part(
        const float* __restrict__ h2, const float* __restrict__ Wr,
        float* __restrict__ partial) {
    __shared__ float As[64][64];
    __shared__ float Bs[64][64];
    const int bid = blockIdx.x;
    const int kc = bid >> 6;
    const int c0 = ((bid >> 3) & 7) * 64;
    const int o0 = (bid & 7) * 64;
    const int k0 = kc * (N_NODES / KSPLIT_F);
    const int tid = threadIdx.x;
    const int tx = tid & 15, ty = tid >> 4;
    float acc[4][4] = {};
    for (int ks = 0; ks < (N_NODES / KSPLIT_F); ks += 64) {
        for (int s = tid; s < 1024; s += 256) {
            int rr = s >> 4;
            int cq = (s & 15) * 4;
            *(float4*)&As[rr][cq] = *(const float4*)&h2[(k0 + ks + rr) * OUT_C + c0 + cq];
            *(float4*)&Bs[rr][cq] = *(const float4*)&Wr[(k0 + ks + rr) * OUT_C + o0 + cq];
        }
        __syncthreads();
#pragma unroll 16
        for (int kk = 0; kk < 64; ++kk) {
            float4 a = *(float4*)&As[kk][ty * 4];
            float4 b = *(float4*)&Bs[kk][tx * 4];
            acc[0][0] = fmaf(a.x, b.x, acc[0][0]); acc[0][1] = fmaf(a.x, b.y, acc[0][1]);
            acc[0][2] = fmaf(a.x, b.z, acc[0][2]); acc[0][3] = fmaf(a.x, b.w, acc[0][3]);
            acc[1][0] = fmaf(a.y, b.x, acc[1][0]); acc[1][1] = fmaf(a.y, b.y, acc[1][1]);
            acc[1][2] = fmaf(a.y, b.z, acc[1][2]); acc[1][3] = fmaf(a.y, b.w, acc[1][3]);
            acc[2][0] = fmaf(a.z, b.x, acc[2][0]); acc[2][1] = fmaf(a.z, b.y, acc[2][1]);
            acc[2][2] = fmaf(a.z, b.z, acc[2][2]); acc[2][3] = fmaf(a.z, b.w, acc[2][3]);
            acc[3][0] = fmaf(a.w, b.x, acc[3][0]); acc[3][1] = fmaf(a.w, b.y, acc[3][1]);
            acc[3][2] = fmaf(a.w, b.z, acc[3][2]); acc[3][3] = fmaf(a.w, b.w, acc[3][3]);
        }
        __syncthreads();
    }
    float* pb = partial + (size_t)kc * (OUT_C * OUT_C);
#pragma unroll
    for (int u = 0; u < 4; ++u) {
        float4 v = {acc[u][0], acc[u][1], acc[u][2], acc[u][3]};
        *(float4*)&pb[(c0 + ty * 4 + u) * OUT_C + o0 + tx * 4] = v;
    }
}

__global__ __launch_bounds__(256) void k_readout_reduce(
        const float* __restrict__ partial, const float* __restrict__ br,
        float* __restrict__ out) {
    int i = blockIdx.x * 256 + threadIdx.x;
    const float4* p4 = (const float4*)partial;
    float4 s = p4[i];
#pragma unroll
    for (int k = 1; k < KSPLIT_F; ++k) {
        float4 t = p4[i + k * 65536];
        s.x += t.x; s.y += t.y; s.z += t.z; s.w += t.w;
    }
    float4 b = ((const float4*)br)[i & 127];
    s.x += b.x; s.y += b.y; s.z += b.z; s.w += b.w;
    ((float4*)out)[i] = s;
}

// ---------------------------------------------------------------------------
extern "C" void kernel_launch(void* const* d_in, const int* in_sizes, int n_in,
                              void* d_out, int out_size, void* d_ws, size_t ws_size,
                              hipStream_t stream) {
    const float* x  = (const float*)d_in[0];
    const int*   ei = (const int*)d_in[1];
    const float* W1 = (const float*)d_in[2];
    const float* b1 = (const float*)d_in[3];
    const float* W2 = (const float*)d_in[4];
    const float* b2 = (const float*)d_in[5];
    const float* W3 = (const float*)d_in[6];
    const float* b3 = (const float*)d_in[7];
    const float* W4 = (const float*)d_in[8];
    const float* b4 = (const float*)d_in[9];
    const float* Wr = (const float*)d_in[10];
    const float* br = (const float*)d_in[11];
    float* out = (float*)d_out;

    char* ws = (char*)d_ws;
    unsigned int* adj = (unsigned int*)ws;                   // 1048576 B (8 copies)
    float* A1 = (float*)(ws + 1048576);                      // 262144 B
    float* B1 = (float*)(ws + 1310720);                      // 262144 B
    float* A2 = (float*)(ws + 1572864);                      // 262144 B
    float* B2 = (float*)(ws + 1835008);                      // 262144 B
    float* h2 = (float*)(ws + 2097152);                      // 2097152 B
    unsigned short* Wpk1 = (unsigned short*)(ws + 4194304);  // 16384 B
    unsigned short* Wpk2 = (unsigned short*)(ws + 4210688);  // 65536 B
    float* partial = (float*)(ws + 4276224);                 // 16777216 B (16 x 1MB)
    // total ~21.1 MB

    MegaParams mp;
    mp.x = x; mp.ei = ei;
    mp.W1 = W1; mp.b1 = b1; mp.W2 = W2; mp.b2 = b2;
    mp.W3 = W3; mp.b3 = b3; mp.W4 = W4; mp.b4 = b4;
    mp.Wr = Wr; mp.br = br;
    mp.adj = adj;
    mp.A1 = A1; mp.B1 = B1; mp.A2 = A2; mp.B2 = B2; mp.h2 = h2;
    mp.Wpk1 = Wpk1; mp.Wpk2 = Wpk2;
    mp.partial = partial;
    mp.out = out;

    void* kargs[] = {(void*)&mp};
    hipError_t err = hipLaunchCooperativeKernel(
        (const void*)k_mega, dim3(1024), dim3(256), kargs, 0, stream);

    if (err != hipSuccess) {
        (void)hipGetLastError();  // clear, fall back to multi-launch path
        k_init<<<dim3(1300), dim3(256), 0, stream>>>(adj, W2, Wpk1, W4, Wpk2,
                                                     x, W1, b1, A1, B1);
        k_build_adj<<<dim3(N_EDGES / 256), dim3(256), 0, stream>>>(ei, adj);
        k_conv_mfma<2, HID_C, true><<<dim3(N_NODES), dim3(256), 0, stream>>>(
            adj, A1, B1, Wpk1, b2, nullptr, W3, b3, A2, B2);
        k_conv_mfma<8, OUT_C, false><<<dim3(N_NODES), dim3(256), 0, stream>>>(
            adj, A2, B2, Wpk2, b4, h2, nullptr, nullptr, nullptr, nullptr);
        k_readout_part<<<dim3(64 * KSPLIT_F), dim3(256), 0, stream>>>(h2, Wr, partial);
        k_readout_reduce<<<dim3(256), dim3(256), 0, stream>>>(partial, br, out);
    }
}

// Round 13
// 172.155 us; speedup vs baseline: 4.3606x; 4.3606x over previous
//
#include <hip/hip_runtime.h>
#include <hip/hip_bf16.h>
#include <float.h>
#include <math.h>

#define N_NODES 1024
#define N_EDGES 524288
#define IN_C    64
#define HID_C   128
#define OUT_C   512
#define MLP_H   64
#define ADJ_WORDS 32   // 1024 bits per dst row
#define KSPLIT  8
#define KCHUNK  (N_NODES / KSPLIT)  // 128

typedef __attribute__((ext_vector_type(8))) short short8;
typedef __attribute__((ext_vector_type(4))) float f32x4;

static __device__ __forceinline__ unsigned short f2bf(float f) {
    __hip_bfloat16 h = __float2bfloat16(f);
    return __builtin_bit_cast(unsigned short, h);
}

// pack fp32 W[64][C] into bf16 MFMA B-fragments: Wpk[nt][kf][lane][8]
// lane l of n-tile nt, k-frag kf supplies W[kf*32 + (l>>4)*8 + e][nt*16 + (l&15)]
static __device__ __forceinline__ void pack_w_one(
        const float* __restrict__ W, unsigned short* __restrict__ Wpk, int C, int idx) {
    int lane = idx & 63;
    int kf = (idx >> 6) & 1;
    int nt = idx >> 7;
    int kbase = kf * 32 + (lane >> 4) * 8;
    int c = nt * 16 + (lane & 15);
#pragma unroll
    for (int e = 0; e < 8; ++e)
        Wpk[idx * 8 + e] = f2bf(W[(kbase + e) * C + c]);
}

// ---------------------------------------------------------------------------
// k_init: range-partitioned fused prologue.
//   blocks [0,128)   : zero adjacency bitmap
//   blocks [128,132) : pack W2 -> Wpk1
//   blocks [132,148) : pack W4 -> Wpk2
//   blocks [148,404) : xform1, 4 nodes/block: A1 = x@W1_top + b1 ; B1 = x@W1_bot
// ---------------------------------------------------------------------------
__global__ __launch_bounds__(256) void k_init(
        unsigned int* __restrict__ adj,
        const float* __restrict__ W2, unsigned short* __restrict__ Wpk1,
        const float* __restrict__ W4, unsigned short* __restrict__ Wpk2,
        const float* __restrict__ x, const float* __restrict__ W1,
        const float* __restrict__ b1,
        float* __restrict__ A1, float* __restrict__ B1) {
    __shared__ float xs[4][IN_C];
    const int b = blockIdx.x, tid = threadIdx.x;
    if (b < 128) {
        adj[b * 256 + tid] = 0u;
        return;
    }
    if (b < 132) { pack_w_one(W2, Wpk1, HID_C, (b - 128) * 256 + tid); return; }
    if (b < 148) { pack_w_one(W4, Wpk2, OUT_C, (b - 132) * 256 + tid); return; }
    const int sub = tid >> 6, t = tid & 63;
    const int n = (b - 148) * 4 + sub;
    xs[sub][t] = x[n * IN_C + t];
    __syncthreads();
    float a = b1[t], bb = 0.f;
#pragma unroll
    for (int k = 0; k < IN_C; ++k) {
        float xv = xs[sub][k];
        a = fmaf(xv, W1[k * MLP_H + t], a);
        bb = fmaf(xv, W1[(IN_C + k) * MLP_H + t], bb);
    }
    A1[n * MLP_H + t] = a;
    B1[n * MLP_H + t] = bb;
}

// single-copy bitmap build (privatization measured neutral in R10)
__global__ void k_build_adj(const int* __restrict__ ei, unsigned int* __restrict__ adj) {
    int e = blockIdx.x * blockDim.x + threadIdx.x;
    if (e >= N_EDGES) return;
    int src = ei[e];            // edge_index[0] = src
    int dst = ei[N_EDGES + e];  // edge_index[1] = dst
    atomicOr(&adj[dst * ADJ_WORDS + (src >> 5)], 1u << (src & 31));
}

// ---------------------------------------------------------------------------
// fused edge-MLP second layer + segment-max via MFMA bf16, cooperative build.
// One block (4 waves) per dst node. LISTMODE=1 (conv1): wave 0 compacts the
// adjacency row via popcount prefix-scan, then the padded list is stored to
// global for reuse. LISTMODE=2 (conv2): list+deg loaded from global — adj
// scan skipped (contents bit-identical by construction). Per batch of BATCH
// edge-tiles: each wave builds BATCH/4 tiles' bf16 A-fragments
// (z = relu(A[dst]+B[src])) into LDS (double-buffered, MFMA fragment layout),
// then ALL waves consume all tiles with register-resident W-fragments
// (setprio(1) around the MFMA cluster). Tail padded with list[0] duplicates
// (max idempotent). FUSEX: conv1 computes A2/B2 in-block (xform2 fused).
// NOTE (measured): launch-boundary is the cheap device barrier on MI355X.
// In-kernel alternatives all lost: fp32 atomics (R5 +30us), threadfence
// last-tile-block (R9 +60us), cooperative grid.sync mega-kernel (R11 +580us).
// ---------------------------------------------------------------------------
template <int NTILES, int C_TOTAL, int BATCH, int MINW, bool FUSEX, int LISTMODE>
__global__ __launch_bounds__(256, MINW) void k_conv_mfma(
        const unsigned int* __restrict__ adj,
        const float* __restrict__ Anode, const float* __restrict__ Bnode,
        const unsigned short* __restrict__ Wpk, const float* __restrict__ bias_g,
        float* __restrict__ outv,
        const float* __restrict__ W3, const float* __restrict__ b3,
        float* __restrict__ A2out, float* __restrict__ B2out,
        unsigned short* __restrict__ listg, int* __restrict__ degg) {
    __shared__ unsigned short list[N_NODES + 16];
    __shared__ short8 zbuf[2][BATCH][2][64];
    __shared__ float hrow[FUSEX ? HID_C : 1];
    __shared__ float xsum[FUSEX ? HID_C : 1];
    __shared__ int cnt;
    const int i = blockIdx.x;
    const int tid = threadIdx.x;
    const int lane = tid & 63;
    const int wave = tid >> 6;   // 0..3
    const int g = lane >> 4;     // lane group 0..3
    const int r = lane & 15;     // row within edge-tile / col within out-tile

    // W fragments + A[dst] slices first: global-load latency hides under the
    // list acquisition below.
    short8 wfr[NTILES][2];
#pragma unroll
    for (int n = 0; n < NTILES; ++n) {
        int nt = wave * NTILES + n;
#pragma unroll
        for (int kf = 0; kf < 2; ++kf)
            wfr[n][kf] = ((const short8*)Wpk)[(nt * 2 + kf) * 64 + lane];
    }
    const f32x4* Ap = (const f32x4*)(Anode + i * MLP_H);
    f32x4 a0 = Ap[g * 2], a1 = Ap[g * 2 + 1], a2 = Ap[8 + g * 2], a3 = Ap[9 + g * 2];

    int deg, padded;
    if constexpr (LISTMODE == 2) {
        // conv2: reuse conv1's compacted list (identical contents by construction)
        if (tid == 0) cnt = degg[i];
        __syncthreads();
        deg = cnt;
        padded = (deg + 15) & ~15;
        for (int p = tid; p < padded; p += 256)
            list[p] = listg[(size_t)i * N_NODES + p];
    } else {
        // conv1: wave 0 popcount prefix-scan compaction of adjacency row
        if (wave == 0) {
            unsigned int bits = (lane < ADJ_WORDS) ? adj[i * ADJ_WORDS + lane] : 0u;
            int c = __popc(bits);
            int pre = c;
#pragma unroll
            for (int d = 1; d < 64; d <<= 1) {
                int t = __shfl_up(pre, d);
                if (lane >= d) pre += t;
            }
            int total = __shfl(pre, 63);
            int pos = pre - c;  // exclusive start
            while (bits) {
                int b = __ffs(bits) - 1;
                bits &= bits - 1;
                list[pos++] = (unsigned short)(lane * 32 + b);
            }
            if (lane == 0) cnt = total;
        }
        __syncthreads();
        deg = cnt;
        padded = (deg + 15) & ~15;
        for (int p = deg + tid; p < padded; p += 256) list[p] = list[0];
    }

    float mx[NTILES];
#pragma unroll
    for (int n = 0; n < NTILES; ++n) mx[n] = -INFINITY;

    // build BATCH/4 edge-tiles per wave into zbuf[buf]
    auto build = [&](int buf, int base_tile, int ntl) {
#pragma unroll
        for (int u = 0; u < BATCH / 4; ++u) {
            int tt = u * 4 + wave;
            if (tt < ntl) {
                int j = list[(base_tile + tt) * 16 + r];
                const f32x4* Bp = (const f32x4*)(Bnode + (size_t)j * MLP_H);
                f32x4 b0 = Bp[g * 2], b1 = Bp[g * 2 + 1], b2 = Bp[8 + g * 2], b3v = Bp[9 + g * 2];
                f32x4 s0 = a0 + b0, s1 = a1 + b1, s2 = a2 + b2, s3 = a3 + b3v;
                short8 z0, z1;
#pragma unroll
                for (int e = 0; e < 4; ++e) {
                    z0[e]     = (short)f2bf(fmaxf(s0[e], 0.f));
                    z0[e + 4] = (short)f2bf(fmaxf(s1[e], 0.f));
                    z1[e]     = (short)f2bf(fmaxf(s2[e], 0.f));
                    z1[e + 4] = (short)f2bf(fmaxf(s3[e], 0.f));
                }
                zbuf[buf][tt][0][lane] = z0;
                zbuf[buf][tt][1][lane] = z1;
            }
        }
    };

    const int ntiles_e = padded >> 4;
    const f32x4 zero = {0.f, 0.f, 0.f, 0.f};

    __syncthreads();  // list (and padding) visible

    if constexpr (LISTMODE == 1) {
        // store padded list + deg for conv2 (fire-and-forget, overlaps build)
        for (int p = tid; p < padded; p += 256)
            listg[(size_t)i * N_NODES + p] = list[p];
        if (tid == 0) degg[i] = deg;
    }

    build(0, 0, min(BATCH, ntiles_e));
    __syncthreads();  // zbuf[0] ready

    int cur = 0;
    for (int b0 = 0; b0 < ntiles_e; b0 += BATCH) {
        int nb = min(BATCH, ntiles_e - b0);
        int nxt = b0 + BATCH;
        if (nxt < ntiles_e) build(cur ^ 1, nxt, min(BATCH, ntiles_e - nxt));
        __builtin_amdgcn_s_setprio(1);
        for (int tt = 0; tt < nb; ++tt) {
            short8 z0 = zbuf[cur][tt][0][lane];
            short8 z1 = zbuf[cur][tt][1][lane];
#pragma unroll
            for (int n = 0; n < NTILES; ++n) {
                f32x4 acc = __builtin_amdgcn_mfma_f32_16x16x32_bf16(z0, wfr[n][0], zero, 0, 0, 0);
                acc = __builtin_amdgcn_mfma_f32_16x16x32_bf16(z1, wfr[n][1], acc, 0, 0, 0);
                // D col = lane&15 (verified layout); rows are max-reduced away
                mx[n] = fmaxf(mx[n], fmaxf(fmaxf(acc[0], acc[1]), fmaxf(acc[2], acc[3])));
            }
        }
        __builtin_amdgcn_s_setprio(0);
        __syncthreads();
        cur ^= 1;
    }

    // combine partial maxes across the 4 lane-groups (same col = lane&15)
#pragma unroll
    for (int n = 0; n < NTILES; ++n) {
        mx[n] = fmaxf(mx[n], __shfl_xor(mx[n], 16));
        mx[n] = fmaxf(mx[n], __shfl_xor(mx[n], 32));
    }
    if (lane < 16) {
#pragma unroll
        for (int n = 0; n < NTILES; ++n) {
            int c = (wave * NTILES + n) * 16 + lane;
            float hv = (deg == 0) ? 0.f : mx[n] + bias_g[c];
            if constexpr (FUSEX) hrow[c] = hv;
            else                 outv[i * C_TOTAL + c] = hv;
        }
    }

    if constexpr (FUSEX) {
        // fused xform2: A2[i] = hrow @ W3[0:128] + b3 ; B2[i] = hrow @ W3[128:256]
        __syncthreads();
        const int c = tid & 63;
        const int half = (tid >> 6) & 1;
        const int ksel = tid >> 7;
        const float* wp = W3 + (half * 128 + ksel * 64) * MLP_H + c;
        float s = 0.f;
#pragma unroll
        for (int k = 0; k < 64; ++k)
            s = fmaf(hrow[ksel * 64 + k], wp[k * MLP_H], s);
        if (ksel) xsum[half * 64 + c] = s;
        __syncthreads();
        if (!ksel) {
            s += xsum[half * 64 + c];
            if (half == 0) A2out[i * MLP_H + c] = s + b3[c];
            else           B2out[i * MLP_H + c] = s;
        }
    }
}

// ---------------------------------------------------------------------------
// readout split-K partials: partial[kc][c][o] = sum_{n in 128-chunk} h2[n][c]*Wr[n][o]
// grid = 64 tiles * KSPLIT(8) = 512 blocks (2/CU). Plain stores; the kernel
// launch boundary is the cheap device-wide barrier.
// ---------------------------------------------------------------------------
__global__ __launch_bounds__(256) void k_readout_part(
        const float* __restrict__ h2, const float* __restrict__ Wr,
        float* __restrict__ partial) {
    __shared__ float As[64][64];
    __shared__ float Bs[64][64];
    const int bid = blockIdx.x;
    const int kc = bid >> 6;
    const int c0 = ((bid >> 3) & 7) * 64;
    const int o0 = (bid & 7) * 64;
    const int k0 = kc * KCHUNK;
    const int tid = threadIdx.x;
    const int tx = tid & 15, ty = tid >> 4;
    float acc[4][4] = {};
    for (int ks = 0; ks < KCHUNK; ks += 64) {
        for (int s = tid; s < 1024; s += 256) {
            int rr = s >> 4;
            int cq = (s & 15) * 4;
            *(float4*)&As[rr][cq] = *(const float4*)&h2[(k0 + ks + rr) * OUT_C + c0 + cq];
            *(float4*)&Bs[rr][cq] = *(const float4*)&Wr[(k0 + ks + rr) * OUT_C + o0 + cq];
        }
        __syncthreads();
#pragma unroll 16
        for (int kk = 0; kk < 64; ++kk) {
            float4 a = *(float4*)&As[kk][ty * 4];
            float4 b = *(float4*)&Bs[kk][tx * 4];
            acc[0][0] = fmaf(a.x, b.x, acc[0][0]); acc[0][1] = fmaf(a.x, b.y, acc[0][1]);
            acc[0][2] = fmaf(a.x, b.z, acc[0][2]); acc[0][3] = fmaf(a.x, b.w, acc[0][3]);
            acc[1][0] = fmaf(a.y, b.x, acc[1][0]); acc[1][1] = fmaf(a.y, b.y, acc[1][1]);
            acc[1][2] = fmaf(a.y, b.z, acc[1][2]); acc[1][3] = fmaf(a.y, b.w, acc[1][3]);
            acc[2][0] = fmaf(a.z, b.x, acc[2][0]); acc[2][1] = fmaf(a.z, b.y, acc[2][1]);
            acc[2][2] = fmaf(a.z, b.z, acc[2][2]); acc[2][3] = fmaf(a.z, b.w, acc[2][3]);
            acc[3][0] = fmaf(a.w, b.x, acc[3][0]); acc[3][1] = fmaf(a.w, b.y, acc[3][1]);
            acc[3][2] = fmaf(a.w, b.z, acc[3][2]); acc[3][3] = fmaf(a.w, b.w, acc[3][3]);
        }
        __syncthreads();
    }
    float* pb = partial + (size_t)kc * (OUT_C * OUT_C);
#pragma unroll
    for (int u = 0; u < 4; ++u) {
        float4 v = {acc[u][0], acc[u][1], acc[u][2], acc[u][3]};
        *(float4*)&pb[(c0 + ty * 4 + u) * OUT_C + o0 + tx * 4] = v;
    }
}

// reduce KSPLIT partials + bias -> out (65536 float4 outputs)
__global__ __launch_bounds__(256) void k_readout_reduce(
        const float* __restrict__ partial, const float* __restrict__ br,
        float* __restrict__ out) {
    int i = blockIdx.x * 256 + threadIdx.x;  // float4 index
    const float4* p4 = (const float4*)partial;
    float4 s = p4[i];
#pragma unroll
    for (int k = 1; k < KSPLIT; ++k) {
        float4 t = p4[i + k * 65536];
        s.x += t.x; s.y += t.y; s.z += t.z; s.w += t.w;
    }
    float4 b = ((const float4*)br)[i & 127];
    s.x += b.x; s.y += b.y; s.z += b.z; s.w += b.w;
    ((float4*)out)[i] = s;
}

// ---------------------------------------------------------------------------
extern "C" void kernel_launch(void* const* d_in, const int* in_sizes, int n_in,
                              void* d_out, int out_size, void* d_ws, size_t ws_size,
                              hipStream_t stream) {
    const float* x  = (const float*)d_in[0];
    const int*   ei = (const int*)d_in[1];
    const float* W1 = (const float*)d_in[2];
    const float* b1 = (const float*)d_in[3];
    const float* W2 = (const float*)d_in[4];
    const float* b2 = (const float*)d_in[5];
    const float* W3 = (const float*)d_in[6];
    const float* b3 = (const float*)d_in[7];
    const float* W4 = (const float*)d_in[8];
    const float* b4 = (const float*)d_in[9];
    const float* Wr = (const float*)d_in[10];
    const float* br = (const float*)d_in[11];
    float* out = (float*)d_out;

    // workspace partition (256B-aligned)
    char* ws = (char*)d_ws;
    unsigned int* adj = (unsigned int*)ws;                  // 131072 B
    float* A1 = (float*)(ws + 131072);                      // 262144 B
    float* B1 = (float*)(ws + 393216);                      // 262144 B
    float* A2 = (float*)(ws + 655360);                      // 262144 B
    float* B2 = (float*)(ws + 917504);                      // 262144 B
    float* h2 = (float*)(ws + 1179648);                     // 2097152 B
    unsigned short* Wpk1 = (unsigned short*)(ws + 3276800); // 16384 B
    unsigned short* Wpk2 = (unsigned short*)(ws + 3293184); // 65536 B
    float* partial = (float*)(ws + 3358720);                // 8388608 B (KSPLIT=8 x 1MB)
    unsigned short* listg = (unsigned short*)(ws + 11747328); // 2097152 B (1024 x 1024 u16)
    int* degg = (int*)(ws + 13844480);                      // 4096 B
    // total 13848576 B

    k_init<<<dim3(404), dim3(256), 0, stream>>>(adj, W2, Wpk1, W4, Wpk2,
                                                x, W1, b1, A1, B1);
    k_build_adj<<<dim3(N_EDGES / 256), dim3(256), 0, stream>>>(ei, adj);
    k_conv_mfma<2, HID_C, 8, 4, true, 1><<<dim3(N_NODES), dim3(256), 0, stream>>>(
        adj, A1, B1, Wpk1, b2, nullptr, W3, b3, A2, B2, listg, degg);
    k_conv_mfma<8, OUT_C, 8, 4, false, 2><<<dim3(N_NODES), dim3(256), 0, stream>>>(
        adj, A2, B2, Wpk2, b4, h2, nullptr, nullptr, nullptr, nullptr, listg, degg);
    k_readout_part<<<dim3(64 * KSPLIT), dim3(256), 0, stream>>>(h2, Wr, partial);
    k_readout_reduce<<<dim3(256), dim3(256), 0, stream>>>(partial, br, out);
}